// Round 7
// baseline (233.053 us; speedup 1.0000x reference)
//
#include <hip/hip_runtime.h>

#define NPTS 16384
#define MPB  16
#define NTHR 512

typedef __attribute__((ext_vector_type(8))) short bf16x8;
typedef __attribute__((ext_vector_type(4))) float f32x4;

// round-to-nearest-even bf16
__device__ __forceinline__ unsigned short f2bf(float x) {
    unsigned u = __float_as_uint(x);
    return (unsigned short)((u + 0x7FFFu + ((u >> 16) & 1u)) >> 16);
}
__device__ __forceinline__ unsigned pack2(float a, float b) {
    unsigned ua = __float_as_uint(a), ub = __float_as_uint(b);
    return ((ua + 0x7FFFu + ((ua >> 16) & 1u)) >> 16) |
           ((ub + 0x7FFFu + ((ub >> 16) & 1u)) & 0xFFFF0000u);
}
__device__ __forceinline__ float bf2f(unsigned short h) {
    return __uint_as_float(((unsigned)h) << 16);
}
__device__ __forceinline__ float elu_f(float x) {
    return x > 0.f ? x : (__expf(x) - 1.f);
}

// Gather one 16x16x32 B-fragment from row-major fp32 W[K][N].
// lane l holds B[kt*32 + (l>>4)*8 + j][nt*16 + (l&15)], j=0..7
__device__ __forceinline__ bf16x8 load_bfrag(const float* __restrict__ W, int N,
                                             int kt, int nt, int lane) {
    int k0  = kt * 32 + ((lane >> 4) << 3);
    int col = nt * 16 + (lane & 15);
    const float* s = W + k0 * N + col;
    union { bf16x8 v; unsigned u[4]; } r;
#pragma unroll
    for (int j = 0; j < 4; j++) r.u[j] = pack2(s[(2 * j) * N], s[(2 * j + 1) * N]);
    return r.v;
}

// LDS map (62720 B, 2 blocks/CU; with 512-thread blocks -> 16 waves/CU):
//  [0,3072)       s_ptsl f32 [16][48]
//  [3072,35840)   s_h2   b16 [256][64]   (rows = m*16+k)
//  [35840,54272)  overlay: h1[128][72] (B) ; x0@35840, x1@44288 (C..E) ; dw[16][520]@35840 (F,G)
//  [54272,62720)  s_x2   b16 [16][264]
__global__ __launch_bounds__(NTHR, 4)
void xconv_main(const float* __restrict__ rep_pt, const float* __restrict__ pts,
                const float* __restrict__ fts,
                const float* __restrict__ w1,  const float* __restrict__ b1,
                const float* __restrict__ w2,  const float* __restrict__ b2,
                const float* __restrict__ wc1, const float* __restrict__ bc1,
                const float* __restrict__ wx1, const float* __restrict__ bx1,
                const float* __restrict__ wx2, const float* __restrict__ bx2,
                const float* __restrict__ wdw, const float* __restrict__ bdw,
                const float* __restrict__ wpw, const float* __restrict__ bpw,
                const float* __restrict__ bn_gamma, const float* __restrict__ bn_beta,
                const float* __restrict__ bn_mean,  const float* __restrict__ bn_var,
                float* __restrict__ out) {
    __shared__ __align__(16) char smem[62720];
    float*          s_ptsl = (float*)smem;                         // [16][48]
    unsigned short* s_h2   = (unsigned short*)(smem + 3072);       // [256][64]
    unsigned short* s_h1   = (unsigned short*)(smem + 35840);      // [128][72]
    unsigned short* s_x0   = (unsigned short*)(smem + 35840);      // [16][264]
    unsigned short* s_x1   = (unsigned short*)(smem + 44288);      // [16][264]
    unsigned short* s_dw   = (unsigned short*)(smem + 35840);      // [16][520]
    unsigned short* s_x2   = (unsigned short*)(smem + 54272);      // [16][264]

    const int t    = threadIdx.x;
    const int lane = t & 63;
    const int w    = t >> 6;        // 8 waves
    const int c0   = lane & 15;
    const int q    = lane >> 4;
    const int gp0  = blockIdx.x * MPB;

    // ---- Phase A: pts_local -> LDS ----
    for (int idx = t; idx < MPB * 48; idx += NTHR) {
        int m = idx / 48, r = idx - m * 48;
        int k = r / 3,    d = r - k * 3;
        int gp = gp0 + m;
        s_ptsl[idx] = pts[(gp * 16 + k) * 3 + d] - rep_pt[gp * 3 + d];
    }
    __syncthreads();

    // ---- Phase B: h1 (VALU, K=3) then h2 = elu(h1@w2+b2) via MFMA ----
    {
        bf16x8 Bf[8];
#pragma unroll
        for (int f = 0; f < 8; f++) Bf[f] = load_bfrag(w2, 64, f >> 2, f & 3, lane);
        float b2v[4];
#pragma unroll
        for (int nt = 0; nt < 4; nt++) b2v[nt] = b2[nt * 16 + c0];

        for (int R = 0; R < 2; R++) {
            {   // h1 half: 4 threads per row, 16 channels each
                int lr  = t >> 2;                 // local row 0..127
                int row = 128 * R + lr;           // global row = m*16+k
                int m = row >> 4, k = row & 15;
                float p0 = s_ptsl[m * 48 + k * 3 + 0];
                float p1 = s_ptsl[m * 48 + k * 3 + 1];
                float p2 = s_ptsl[m * 48 + k * 3 + 2];
                int cb = (t & 3) * 16;
#pragma unroll
                for (int cc = 0; cc < 2; cc++) {
                    unsigned v[4];
#pragma unroll
                    for (int u = 0; u < 4; u++) {
                        int ci = cb + cc * 8 + u * 2;
                        float a  = fmaf(p0, w1[ci],     fmaf(p1, w1[64 + ci],     fmaf(p2, w1[128 + ci],     b1[ci])));
                        float bb = fmaf(p0, w1[ci + 1], fmaf(p1, w1[64 + ci + 1], fmaf(p2, w1[128 + ci + 1], b1[ci + 1])));
                        v[u] = pack2(elu_f(a), elu_f(bb));
                    }
                    *(uint4*)&s_h1[lr * 72 + cb + cc * 8] = make_uint4(v[0], v[1], v[2], v[3]);
                }
            }
            __syncthreads();
            {   // MFMA: wave w does row-tile rtl = w  (one 16-row tile per wave)
                int g0 = (8 * R + w) * 16;        // global row base
                bf16x8 a0 = *(const bf16x8*)&s_h1[(w * 16 + c0) * 72 + 0  + q * 8];
                bf16x8 a1 = *(const bf16x8*)&s_h1[(w * 16 + c0) * 72 + 32 + q * 8];
#pragma unroll
                for (int nt = 0; nt < 4; nt++) {
                    f32x4 acc = {b2v[nt], b2v[nt], b2v[nt], b2v[nt]};
                    acc = __builtin_amdgcn_mfma_f32_16x16x32_bf16(a0, Bf[nt],     acc, 0, 0, 0);
                    acc = __builtin_amdgcn_mfma_f32_16x16x32_bf16(a1, Bf[4 + nt], acc, 0, 0, 0);
#pragma unroll
                    for (int r = 0; r < 4; r++) {
                        int krow = q * 4 + r;
                        s_h2[(g0 + krow) * 64 + nt * 16 + c0] = f2bf(elu_f(acc[r]));
                    }
                }
            }
            __syncthreads();
        }
    }

    // ---- Phase C: X0 = elu(ptsl einsum wc1 + bc1) (VALU) ----
    {
        int o    = t & 255;
        int half = t >> 8;                    // 2 threads per channel, 8 points each
        float wreg[48];                       // wc1[o][d][k] -> wreg[d*16+k]
#pragma unroll
        for (int qq = 0; qq < 12; qq++) {
            float4 wv = *(const float4*)&wc1[o * 48 + qq * 4];
            wreg[qq * 4 + 0] = wv.x; wreg[qq * 4 + 1] = wv.y;
            wreg[qq * 4 + 2] = wv.z; wreg[qq * 4 + 3] = wv.w;
        }
        float bo = bc1[o];
#pragma unroll 1
        for (int mm = 0; mm < 8; mm++) {
            int m = half * 8 + mm;
            float acc = bo;
#pragma unroll
            for (int qq = 0; qq < 12; qq++) {
                float4 pv = *(const float4*)&s_ptsl[m * 48 + qq * 4];   // flat f = k*3+d
                acc = fmaf(pv.x, wreg[((qq * 4 + 0) % 3) * 16 + (qq * 4 + 0) / 3], acc);
                acc = fmaf(pv.y, wreg[((qq * 4 + 1) % 3) * 16 + (qq * 4 + 1) / 3], acc);
                acc = fmaf(pv.z, wreg[((qq * 4 + 2) % 3) * 16 + (qq * 4 + 2) / 3], acc);
                acc = fmaf(pv.w, wreg[((qq * 4 + 3) % 3) * 16 + (qq * 4 + 3) / 3], acc);
            }
            s_x0[m * 264 + o] = f2bf(elu_f(acc));
        }
    }
    __syncthreads();

    // ---- Phase D: X1 = elu(X0 @ wx1 + bx1), MFMA M=16,N=256,K=256 ----
    {
        f32x4 acc[2];
#pragma unroll
        for (int p = 0; p < 2; p++) {
            float bv = bx1[(w * 2 + p) * 16 + c0];
            acc[p] = (f32x4){bv, bv, bv, bv};
        }
#pragma unroll
        for (int kt = 0; kt < 8; kt++) {
            bf16x8 a = *(const bf16x8*)&s_x0[c0 * 264 + kt * 32 + q * 8];
#pragma unroll
            for (int p = 0; p < 2; p++) {
                bf16x8 b = load_bfrag(wx1, 256, kt, w * 2 + p, lane);
                acc[p] = __builtin_amdgcn_mfma_f32_16x16x32_bf16(a, b, acc[p], 0, 0, 0);
            }
        }
#pragma unroll
        for (int p = 0; p < 2; p++) {
            int nt = w * 2 + p;
#pragma unroll
            for (int r = 0; r < 4; r++) {
                int m = q * 4 + r;
                s_x1[m * 264 + nt * 16 + c0] = f2bf(elu_f(acc[p][r]));
            }
        }
    }
    __syncthreads();

    // ---- Phase E: X2 = X1 @ wx2 + bx2 (no act), MFMA ----
    {
        f32x4 acc[2];
#pragma unroll
        for (int p = 0; p < 2; p++) {
            float bv = bx2[(w * 2 + p) * 16 + c0];
            acc[p] = (f32x4){bv, bv, bv, bv};
        }
#pragma unroll
        for (int kt = 0; kt < 8; kt++) {
            bf16x8 a = *(const bf16x8*)&s_x1[c0 * 264 + kt * 32 + q * 8];
#pragma unroll
            for (int p = 0; p < 2; p++) {
                bf16x8 b = load_bfrag(wx2, 256, kt, w * 2 + p, lane);
                acc[p] = __builtin_amdgcn_mfma_f32_16x16x32_bf16(a, b, acc[p], 0, 0, 0);
            }
        }
#pragma unroll
        for (int p = 0; p < 2; p++) {
            int nt = w * 2 + p;
#pragma unroll
            for (int r = 0; r < 4; r++) {
                int m = q * 4 + r;
                s_x2[m * 264 + nt * 16 + c0] = f2bf(acc[p][r]);
            }
        }
    }
    __syncthreads();

    // ---- Phase F: fts_X = X2 @ fts_cat  +  depthwise (VALU, R3-exact ops) ----
    {
        const int c  = t & 127;
        const int mg = t >> 7;                 // 0..3 ; each thread does 4 points
        float wd[64];
#pragma unroll
        for (int qq = 0; qq < 16; qq++) {
            float4 v = *(const float4*)&wdw[c * 64 + qq * 4];
            wd[qq * 4 + 0] = v.x; wd[qq * 4 + 1] = v.y;
            wd[qq * 4 + 2] = v.z; wd[qq * 4 + 3] = v.w;
        }
        float bd[4];
#pragma unroll
        for (int d = 0; d < 4; d++) bd[d] = bdw[c * 4 + d];
#pragma unroll 1
        for (int ml = 0; ml < 4; ml++) {
            int m  = mg * 4 + ml;
            int gp = gp0 + m;
            float fc[16];
            if (c < 64) {
#pragma unroll
                for (int j = 0; j < 16; j++) fc[j] = bf2f(s_h2[(m * 16 + j) * 64 + c]);
            } else {
#pragma unroll
                for (int j = 0; j < 16; j++) fc[j] = fts[(gp * 16 + j) * 64 + (c - 64)];
            }
            float fXr[16];
#pragma unroll
            for (int i = 0; i < 16; i++) {
                float a = 0.f;
#pragma unroll
                for (int jj = 0; jj < 2; jj++) {
                    uint4 xv = *(const uint4*)&s_x2[m * 264 + i * 16 + jj * 8];
                    a = fmaf(__uint_as_float(xv.x << 16),          fc[jj * 8 + 0], a);
                    a = fmaf(__uint_as_float(xv.x & 0xFFFF0000u),  fc[jj * 8 + 1], a);
                    a = fmaf(__uint_as_float(xv.y << 16),          fc[jj * 8 + 2], a);
                    a = fmaf(__uint_as_float(xv.y & 0xFFFF0000u),  fc[jj * 8 + 3], a);
                    a = fmaf(__uint_as_float(xv.z << 16),          fc[jj * 8 + 4], a);
                    a = fmaf(__uint_as_float(xv.z & 0xFFFF0000u),  fc[jj * 8 + 5], a);
                    a = fmaf(__uint_as_float(xv.w << 16),          fc[jj * 8 + 6], a);
                    a = fmaf(__uint_as_float(xv.w & 0xFFFF0000u),  fc[jj * 8 + 7], a);
                }
                fXr[i] = a;
            }
            ushort4 dv;
            {
                float o[4];
#pragma unroll
                for (int d = 0; d < 4; d++) {
                    float a = bd[d];
#pragma unroll
                    for (int k = 0; k < 16; k++) a = fmaf(fXr[k], wd[d * 16 + k], a);
                    o[d] = a;
                }
                dv.x = f2bf(o[0]); dv.y = f2bf(o[1]); dv.z = f2bf(o[2]); dv.w = f2bf(o[3]);
            }
            *(ushort4*)&s_dw[m * 520 + c * 4] = dv;
        }
    }
    __syncthreads();

    // ---- Phase G: y = BN(elu(dw @ wpw + bpw)), MFMA M=16,N=128,K=512 ----
    {
        float bv = bpw[w * 16 + c0];
        f32x4 acc = {bv, bv, bv, bv};
#pragma unroll
        for (int kt = 0; kt < 16; kt++) {
            bf16x8 a = *(const bf16x8*)&s_dw[c0 * 520 + kt * 32 + q * 8];
            bf16x8 b = load_bfrag(wpw, 128, kt, w, lane);
            acc = __builtin_amdgcn_mfma_f32_16x16x32_bf16(a, b, acc, 0, 0, 0);
        }
        int co = w * 16 + c0;
        float scale = bn_gamma[co] * rsqrtf(bn_var[co] + 1e-5f);
        float shift = bn_beta[co] - bn_mean[co] * scale;
#pragma unroll
        for (int r = 0; r < 4; r++) {
            int m = q * 4 + r;
            out[(size_t)(gp0 + m) * 128 + co] = fmaf(elu_f(acc[r]), scale, shift);
        }
    }
}

extern "C" void kernel_launch(void* const* d_in, const int* in_sizes, int n_in,
                              void* d_out, int out_size, void* d_ws, size_t ws_size,
                              hipStream_t stream) {
    const float* rep_pt   = (const float*)d_in[0];
    const float* pts      = (const float*)d_in[1];
    const float* fts      = (const float*)d_in[2];
    const float* w1       = (const float*)d_in[3];
    const float* b1       = (const float*)d_in[4];
    const float* w2       = (const float*)d_in[5];
    const float* b2       = (const float*)d_in[6];
    const float* wc1      = (const float*)d_in[7];
    const float* bc1      = (const float*)d_in[8];
    const float* wx1      = (const float*)d_in[9];
    const float* bx1      = (const float*)d_in[10];
    const float* wx2      = (const float*)d_in[11];
    const float* bx2      = (const float*)d_in[12];
    const float* wdw      = (const float*)d_in[13];
    const float* bdw      = (const float*)d_in[14];
    const float* wpw      = (const float*)d_in[15];
    const float* bpw      = (const float*)d_in[16];
    const float* bn_gamma = (const float*)d_in[17];
    const float* bn_beta  = (const float*)d_in[18];
    const float* bn_mean  = (const float*)d_in[19];
    const float* bn_var   = (const float*)d_in[20];
    float* out = (float*)d_out;

    xconv_main<<<NPTS / MPB, NTHR, 0, stream>>>(
        rep_pt, pts, fts, w1, b1, w2, b2, wc1, bc1, wx1, bx1, wx2, bx2,
        wdw, bdw, wpw, bpw, bn_gamma, bn_beta, bn_mean, bn_var, out);
}

// Round 8
// 222.117 us; speedup vs baseline: 1.0492x; 1.0492x over previous
//
#include <hip/hip_runtime.h>

#define NPTS 16384
#define MPB  32
#define NTHR 512
#define LDS_TOTAL 122368

typedef __attribute__((ext_vector_type(8))) short bf16x8;
typedef __attribute__((ext_vector_type(4))) float f32x4;

// round-to-nearest-even bf16
__device__ __forceinline__ unsigned short f2bf(float x) {
    unsigned u = __float_as_uint(x);
    return (unsigned short)((u + 0x7FFFu + ((u >> 16) & 1u)) >> 16);
}
__device__ __forceinline__ unsigned pack2(float a, float b) {
    unsigned ua = __float_as_uint(a), ub = __float_as_uint(b);
    return ((ua + 0x7FFFu + ((ua >> 16) & 1u)) >> 16) |
           ((ub + 0x7FFFu + ((ub >> 16) & 1u)) & 0xFFFF0000u);
}
__device__ __forceinline__ float bf2f(unsigned short h) {
    return __uint_as_float(((unsigned)h) << 16);
}
__device__ __forceinline__ float elu_f(float x) {
    return x > 0.f ? x : (__expf(x) - 1.f);
}

// Gather one 16x16x32 B-fragment from row-major fp32 W[K][N].
// lane l holds B[kt*32 + (l>>4)*8 + j][nt*16 + (l&15)], j=0..7
__device__ __forceinline__ bf16x8 load_bfrag(const float* __restrict__ W, int N,
                                             int kt, int nt, int lane) {
    int k0  = kt * 32 + ((lane >> 4) << 3);
    int col = nt * 16 + (lane & 15);
    const float* s = W + k0 * N + col;
    union { bf16x8 v; unsigned u[4]; } r;
#pragma unroll
    for (int j = 0; j < 4; j++) r.u[j] = pack2(s[(2 * j) * N], s[(2 * j + 1) * N]);
    return r.v;
}

// Dynamic LDS map (122368 B, 1 block/CU, 8 waves):
//  [0,6144)        s_ptsl f32 [32][48]
//  [6144,71680)    s_h2   b16 [512][64]   (rows = m*16+k, m=0..31)
//  [71680,88576)   s_x2   b16 [32][264]
//  [88576,122368)  overlay: h1[128][72] (B rounds) ; x0@88576 [32][264], x1@105472 [32][264] (C..E);
//                           dw[32][520]@88576 (F,G)
__global__ __launch_bounds__(NTHR, 2)
void xconv_main(const float* __restrict__ rep_pt, const float* __restrict__ pts,
                const float* __restrict__ fts,
                const float* __restrict__ w1,  const float* __restrict__ b1,
                const float* __restrict__ w2,  const float* __restrict__ b2,
                const float* __restrict__ wc1, const float* __restrict__ bc1,
                const float* __restrict__ wx1, const float* __restrict__ bx1,
                const float* __restrict__ wx2, const float* __restrict__ bx2,
                const float* __restrict__ wdw, const float* __restrict__ bdw,
                const float* __restrict__ wpw, const float* __restrict__ bpw,
                const float* __restrict__ bn_gamma, const float* __restrict__ bn_beta,
                const float* __restrict__ bn_mean,  const float* __restrict__ bn_var,
                float* __restrict__ out) {
    extern __shared__ __align__(16) char smem[];
    float*          s_ptsl = (float*)smem;                          // [32][48]
    unsigned short* s_h2   = (unsigned short*)(smem + 6144);        // [512][64]
    unsigned short* s_x2   = (unsigned short*)(smem + 71680);       // [32][264]
    unsigned short* s_h1   = (unsigned short*)(smem + 88576);       // [128][72]
    unsigned short* s_x0   = (unsigned short*)(smem + 88576);       // [32][264]
    unsigned short* s_x1   = (unsigned short*)(smem + 105472);      // [32][264]
    unsigned short* s_dw   = (unsigned short*)(smem + 88576);       // [32][520]

    const int t    = threadIdx.x;
    const int lane = t & 63;
    const int w    = t >> 6;        // 8 waves
    const int c0   = lane & 15;
    const int q    = lane >> 4;
    const int gp0  = blockIdx.x * MPB;

    // ---- Phase A: pts_local -> LDS (32 points) ----
    for (int idx = t; idx < MPB * 48; idx += NTHR) {
        int m = idx / 48, r = idx - m * 48;
        int k = r / 3,    d = r - k * 3;
        int gp = gp0 + m;
        s_ptsl[idx] = pts[(gp * 16 + k) * 3 + d] - rep_pt[gp * 3 + d];
    }
    __syncthreads();

    // ---- Phase B: h1 (VALU, K=3) then h2 = elu(h1@w2+b2) via MFMA, 4 rounds ----
    {
        bf16x8 Bf[8];                       // hoisted: loaded once per wave for all 4 rounds
#pragma unroll
        for (int f = 0; f < 8; f++) Bf[f] = load_bfrag(w2, 64, f >> 2, f & 3, lane);
        float b2v[4];
#pragma unroll
        for (int nt = 0; nt < 4; nt++) b2v[nt] = b2[nt * 16 + c0];

        for (int R = 0; R < 4; R++) {
            {   // h1 round: 128 rows, 4 threads per row, 16 channels each
                int lr  = t >> 2;                 // local row 0..127
                int m = 8 * R + (lr >> 4);        // point
                int k = lr & 15;
                float p0 = s_ptsl[m * 48 + k * 3 + 0];
                float p1 = s_ptsl[m * 48 + k * 3 + 1];
                float p2 = s_ptsl[m * 48 + k * 3 + 2];
                int cb = (t & 3) * 16;
#pragma unroll
                for (int cc = 0; cc < 2; cc++) {
                    unsigned v[4];
#pragma unroll
                    for (int u = 0; u < 4; u++) {
                        int ci = cb + cc * 8 + u * 2;
                        float a  = fmaf(p0, w1[ci],     fmaf(p1, w1[64 + ci],     fmaf(p2, w1[128 + ci],     b1[ci])));
                        float bb = fmaf(p0, w1[ci + 1], fmaf(p1, w1[64 + ci + 1], fmaf(p2, w1[128 + ci + 1], b1[ci + 1])));
                        v[u] = pack2(elu_f(a), elu_f(bb));
                    }
                    *(uint4*)&s_h1[lr * 72 + cb + cc * 8] = make_uint4(v[0], v[1], v[2], v[3]);
                }
            }
            __syncthreads();
            {   // MFMA: wave w does row-tile w of this round (point m = 8R + w)
                int m = 8 * R + w;
                bf16x8 a0 = *(const bf16x8*)&s_h1[(w * 16 + c0) * 72 + 0  + q * 8];
                bf16x8 a1 = *(const bf16x8*)&s_h1[(w * 16 + c0) * 72 + 32 + q * 8];
#pragma unroll
                for (int nt = 0; nt < 4; nt++) {
                    f32x4 acc = {b2v[nt], b2v[nt], b2v[nt], b2v[nt]};
                    acc = __builtin_amdgcn_mfma_f32_16x16x32_bf16(a0, Bf[nt],     acc, 0, 0, 0);
                    acc = __builtin_amdgcn_mfma_f32_16x16x32_bf16(a1, Bf[4 + nt], acc, 0, 0, 0);
#pragma unroll
                    for (int r = 0; r < 4; r++) {
                        s_h2[(m * 16 + q * 4 + r) * 64 + nt * 16 + c0] = f2bf(elu_f(acc[r]));
                    }
                }
            }
            __syncthreads();
        }
    }

    // ---- Phase C: X0 = elu(ptsl einsum wc1 + bc1) (VALU) ----
    {
        int o    = t & 255;
        int half = t >> 8;                    // 16 points per thread
        float wreg[48];                       // wc1[o][d][k] -> wreg[d*16+k]
#pragma unroll
        for (int qq = 0; qq < 12; qq++) {
            float4 wv = *(const float4*)&wc1[o * 48 + qq * 4];
            wreg[qq * 4 + 0] = wv.x; wreg[qq * 4 + 1] = wv.y;
            wreg[qq * 4 + 2] = wv.z; wreg[qq * 4 + 3] = wv.w;
        }
        float bo = bc1[o];
#pragma unroll 1
        for (int mm = 0; mm < 16; mm++) {
            int m = half * 16 + mm;
            float acc = bo;
#pragma unroll
            for (int qq = 0; qq < 12; qq++) {
                float4 pv = *(const float4*)&s_ptsl[m * 48 + qq * 4];   // flat f = k*3+d
                acc = fmaf(pv.x, wreg[((qq * 4 + 0) % 3) * 16 + (qq * 4 + 0) / 3], acc);
                acc = fmaf(pv.y, wreg[((qq * 4 + 1) % 3) * 16 + (qq * 4 + 1) / 3], acc);
                acc = fmaf(pv.z, wreg[((qq * 4 + 2) % 3) * 16 + (qq * 4 + 2) / 3], acc);
                acc = fmaf(pv.w, wreg[((qq * 4 + 3) % 3) * 16 + (qq * 4 + 3) / 3], acc);
            }
            s_x0[m * 264 + o] = f2bf(elu_f(acc));
        }
    }
    __syncthreads();

    // ---- Phase D: X1 = elu(X0 @ wx1 + bx1), MFMA, frags shared across halves ----
    {
        f32x4 acc[2][2];
#pragma unroll
        for (int p = 0; p < 2; p++) {
            float bv = bx1[(w * 2 + p) * 16 + c0];
            acc[0][p] = (f32x4){bv, bv, bv, bv};
            acc[1][p] = (f32x4){bv, bv, bv, bv};
        }
#pragma unroll
        for (int kt = 0; kt < 8; kt++) {
            bf16x8 a0 = *(const bf16x8*)&s_x0[(c0) * 264 + kt * 32 + q * 8];
            bf16x8 a1 = *(const bf16x8*)&s_x0[(16 + c0) * 264 + kt * 32 + q * 8];
#pragma unroll
            for (int p = 0; p < 2; p++) {
                bf16x8 b = load_bfrag(wx1, 256, kt, w * 2 + p, lane);
                acc[0][p] = __builtin_amdgcn_mfma_f32_16x16x32_bf16(a0, b, acc[0][p], 0, 0, 0);
                acc[1][p] = __builtin_amdgcn_mfma_f32_16x16x32_bf16(a1, b, acc[1][p], 0, 0, 0);
            }
        }
#pragma unroll
        for (int half = 0; half < 2; half++)
#pragma unroll
            for (int p = 0; p < 2; p++) {
                int nt = w * 2 + p;
#pragma unroll
                for (int r = 0; r < 4; r++) {
                    int m = half * 16 + q * 4 + r;
                    s_x1[m * 264 + nt * 16 + c0] = f2bf(elu_f(acc[half][p][r]));
                }
            }
    }
    __syncthreads();

    // ---- Phase E: X2 = X1 @ wx2 + bx2 (no act), MFMA ----
    {
        f32x4 acc[2][2];
#pragma unroll
        for (int p = 0; p < 2; p++) {
            float bv = bx2[(w * 2 + p) * 16 + c0];
            acc[0][p] = (f32x4){bv, bv, bv, bv};
            acc[1][p] = (f32x4){bv, bv, bv, bv};
        }
#pragma unroll
        for (int kt = 0; kt < 8; kt++) {
            bf16x8 a0 = *(const bf16x8*)&s_x1[(c0) * 264 + kt * 32 + q * 8];
            bf16x8 a1 = *(const bf16x8*)&s_x1[(16 + c0) * 264 + kt * 32 + q * 8];
#pragma unroll
            for (int p = 0; p < 2; p++) {
                bf16x8 b = load_bfrag(wx2, 256, kt, w * 2 + p, lane);
                acc[0][p] = __builtin_amdgcn_mfma_f32_16x16x32_bf16(a0, b, acc[0][p], 0, 0, 0);
                acc[1][p] = __builtin_amdgcn_mfma_f32_16x16x32_bf16(a1, b, acc[1][p], 0, 0, 0);
            }
        }
#pragma unroll
        for (int half = 0; half < 2; half++)
#pragma unroll
            for (int p = 0; p < 2; p++) {
                int nt = w * 2 + p;
#pragma unroll
                for (int r = 0; r < 4; r++) {
                    int m = half * 16 + q * 4 + r;
                    s_x2[m * 264 + nt * 16 + c0] = f2bf(acc[half][p][r]);
                }
            }
    }
    __syncthreads();

    // ---- Phase F: fts_X = X2 @ fts_cat  +  depthwise (VALU, R3-exact ops) ----
    {
        const int c = t & 127;
        const int g = t >> 7;                  // 0..3 ; each thread does 8 points
        float wd[64];
#pragma unroll
        for (int qq = 0; qq < 16; qq++) {
            float4 v = *(const float4*)&wdw[c * 64 + qq * 4];
            wd[qq * 4 + 0] = v.x; wd[qq * 4 + 1] = v.y;
            wd[qq * 4 + 2] = v.z; wd[qq * 4 + 3] = v.w;
        }
        float bd[4];
#pragma unroll
        for (int d = 0; d < 4; d++) bd[d] = bdw[c * 4 + d];
#pragma unroll 1
        for (int ml = 0; ml < 8; ml++) {
            int m  = g * 8 + ml;
            int gp = gp0 + m;
            float fc[16];
            if (c < 64) {
#pragma unroll
                for (int j = 0; j < 16; j++) fc[j] = bf2f(s_h2[(m * 16 + j) * 64 + c]);
            } else {
#pragma unroll
                for (int j = 0; j < 16; j++) fc[j] = fts[(gp * 16 + j) * 64 + (c - 64)];
            }
            float fXr[16];
#pragma unroll
            for (int i = 0; i < 16; i++) {
                float a = 0.f;
#pragma unroll
                for (int jj = 0; jj < 2; jj++) {
                    uint4 xv = *(const uint4*)&s_x2[m * 264 + i * 16 + jj * 8];
                    a = fmaf(__uint_as_float(xv.x << 16),          fc[jj * 8 + 0], a);
                    a = fmaf(__uint_as_float(xv.x & 0xFFFF0000u),  fc[jj * 8 + 1], a);
                    a = fmaf(__uint_as_float(xv.y << 16),          fc[jj * 8 + 2], a);
                    a = fmaf(__uint_as_float(xv.y & 0xFFFF0000u),  fc[jj * 8 + 3], a);
                    a = fmaf(__uint_as_float(xv.z << 16),          fc[jj * 8 + 4], a);
                    a = fmaf(__uint_as_float(xv.z & 0xFFFF0000u),  fc[jj * 8 + 5], a);
                    a = fmaf(__uint_as_float(xv.w << 16),          fc[jj * 8 + 6], a);
                    a = fmaf(__uint_as_float(xv.w & 0xFFFF0000u),  fc[jj * 8 + 7], a);
                }
                fXr[i] = a;
            }
            ushort4 dv;
            {
                float o[4];
#pragma unroll
                for (int d = 0; d < 4; d++) {
                    float a = bd[d];
#pragma unroll
                    for (int k = 0; k < 16; k++) a = fmaf(fXr[k], wd[d * 16 + k], a);
                    o[d] = a;
                }
                dv.x = f2bf(o[0]); dv.y = f2bf(o[1]); dv.z = f2bf(o[2]); dv.w = f2bf(o[3]);
            }
            *(ushort4*)&s_dw[m * 520 + c * 4] = dv;
        }
    }
    __syncthreads();

    // ---- Phase G: y = BN(elu(dw @ wpw + bpw)), MFMA, frags shared across halves ----
    {
        float bv = bpw[w * 16 + c0];
        f32x4 acc0 = {bv, bv, bv, bv};
        f32x4 acc1 = {bv, bv, bv, bv};
#pragma unroll
        for (int kt = 0; kt < 16; kt++) {
            bf16x8 b  = load_bfrag(wpw, 128, kt, w, lane);
            bf16x8 a0 = *(const bf16x8*)&s_dw[(c0) * 520 + kt * 32 + q * 8];
            bf16x8 a1 = *(const bf16x8*)&s_dw[(16 + c0) * 520 + kt * 32 + q * 8];
            acc0 = __builtin_amdgcn_mfma_f32_16x16x32_bf16(a0, b, acc0, 0, 0, 0);
            acc1 = __builtin_amdgcn_mfma_f32_16x16x32_bf16(a1, b, acc1, 0, 0, 0);
        }
        int co = w * 16 + c0;
        float scale = bn_gamma[co] * rsqrtf(bn_var[co] + 1e-5f);
        float shift = bn_beta[co] - bn_mean[co] * scale;
#pragma unroll
        for (int r = 0; r < 4; r++) {
            out[(size_t)(gp0 + q * 4 + r) * 128 + co]      = fmaf(elu_f(acc0[r]), scale, shift);
            out[(size_t)(gp0 + 16 + q * 4 + r) * 128 + co] = fmaf(elu_f(acc1[r]), scale, shift);
        }
    }
}

extern "C" void kernel_launch(void* const* d_in, const int* in_sizes, int n_in,
                              void* d_out, int out_size, void* d_ws, size_t ws_size,
                              hipStream_t stream) {
    const float* rep_pt   = (const float*)d_in[0];
    const float* pts      = (const float*)d_in[1];
    const float* fts      = (const float*)d_in[2];
    const float* w1       = (const float*)d_in[3];
    const float* b1       = (const float*)d_in[4];
    const float* w2       = (const float*)d_in[5];
    const float* b2       = (const float*)d_in[6];
    const float* wc1      = (const float*)d_in[7];
    const float* bc1      = (const float*)d_in[8];
    const float* wx1      = (const float*)d_in[9];
    const float* bx1      = (const float*)d_in[10];
    const float* wx2      = (const float*)d_in[11];
    const float* bx2      = (const float*)d_in[12];
    const float* wdw      = (const float*)d_in[13];
    const float* bdw      = (const float*)d_in[14];
    const float* wpw      = (const float*)d_in[15];
    const float* bpw      = (const float*)d_in[16];
    const float* bn_gamma = (const float*)d_in[17];
    const float* bn_beta  = (const float*)d_in[18];
    const float* bn_mean  = (const float*)d_in[19];
    const float* bn_var   = (const float*)d_in[20];
    float* out = (float*)d_out;

    static int attr_done = 0;   // idempotent attribute set (same value every call)
    (void)hipFuncSetAttribute((const void*)xconv_main,
                              hipFuncAttributeMaxDynamicSharedMemorySize, LDS_TOTAL);
    (void)attr_done;

    xconv_main<<<NPTS / MPB, NTHR, LDS_TOTAL, stream>>>(
        rep_pt, pts, fts, w1, b1, w2, b2, wc1, bc1, wx1, bx1, wx2, bx2,
        wdw, bdw, wpw, bpw, bn_gamma, bn_beta, bn_mean, bn_var, out);
}